// Round 1
// baseline (457.556 us; speedup 1.0000x reference)
//
#include <hip/hip_runtime.h>
#include <cstdint>
#include <cstddef>

// ---------------- common types / helpers ----------------
typedef __bf16 bf16x8 __attribute__((ext_vector_type(8)));
typedef float  f32x4  __attribute__((ext_vector_type(4)));

__device__ __forceinline__ void load16_to_lds(const void* g, void* l) {
  __builtin_amdgcn_global_load_lds(
      (const __attribute__((address_space(1))) void*)g,
      (__attribute__((address_space(3))) void*)l, 16, 0, 0);
}

// ---------------- weight cast+transpose: f32 (K,N) -> bf16 (N,K) ----------------
__global__ __launch_bounds__(256) void transpose_cast(
    const float* __restrict__ src, __bf16* __restrict__ dst, int K, int N)
{
  __shared__ float tile[32][33];
  const int n0 = blockIdx.x * 32, k0 = blockIdx.y * 32;
  const int tx = threadIdx.x, ty = threadIdx.y; // (32,8)
#pragma unroll
  for (int i = 0; i < 32; i += 8)
    tile[ty + i][tx] = src[(size_t)(k0 + ty + i) * N + n0 + tx];
  __syncthreads();
#pragma unroll
  for (int i = 0; i < 32; i += 8)
    dst[(size_t)(n0 + ty + i) * K + k0 + tx] = (__bf16)tile[tx][ty + i];
}

// ---------------- LayerNorm: f32 row(1024) -> bf16 ----------------
__global__ __launch_bounds__(256) void ln_kernel(
    const float* __restrict__ x, const float* __restrict__ g,
    const float* __restrict__ bta, __bf16* __restrict__ out)
{
  const int row = blockIdx.x;
  const int t = threadIdx.x;
  const float4 v = ((const float4*)(x + (size_t)row * 1024))[t];
  float s  = v.x + v.y + v.z + v.w;
  float ss = v.x * v.x + v.y * v.y + v.z * v.z + v.w * v.w;
#pragma unroll
  for (int o = 32; o > 0; o >>= 1) { s += __shfl_down(s, o); ss += __shfl_down(ss, o); }
  __shared__ float rs[4], rss[4];
  const int w = t >> 6, l = t & 63;
  if (l == 0) { rs[w] = s; rss[w] = ss; }
  __syncthreads();
  s  = rs[0] + rs[1] + rs[2] + rs[3];
  ss = rss[0] + rss[1] + rss[2] + rss[3];
  const float mu = s * (1.0f / 1024.0f);
  const float var = ss * (1.0f / 1024.0f) - mu * mu;
  const float rstd = rsqrtf(var + 1e-5f);
  const float4 gg = ((const float4*)g)[t];
  const float4 bb = ((const float4*)bta)[t];
  __bf16* o = out + (size_t)row * 1024 + t * 4;
  o[0] = (__bf16)((v.x - mu) * rstd * gg.x + bb.x);
  o[1] = (__bf16)((v.y - mu) * rstd * gg.y + bb.y);
  o[2] = (__bf16)((v.z - mu) * rstd * gg.z + bb.z);
  o[3] = (__bf16)((v.w - mu) * rstd * gg.w + bb.w);
}

// ---------------- bf16 MFMA GEMM: C = A(MxK) * Bt(NxK)^T ----------------
enum { EPI_BF16 = 0, EPI_RES_F32 = 1, EPI_GELU_BF16 = 2, EPI_BIAS_RES_F32 = 3 };

template <int EPI>
__global__ __launch_bounds__(256, 2) void gemm_bf16(
    const __bf16* __restrict__ A, const __bf16* __restrict__ Bt,
    __bf16* __restrict__ outb, float* __restrict__ outf,
    const float* __restrict__ bias, const float* __restrict__ res,
    int M, int N, int K)
{
  __shared__ __bf16 As[128 * 32];
  __shared__ __bf16 Bs[128 * 32];
  const int tid  = threadIdx.x;
  const int lane = tid & 63, w = tid >> 6;
  const int wm = w >> 1, wn = w & 1;
  const int quad = lane >> 4, l16 = lane & 15;
  const int m0 = blockIdx.y * 128, n0 = blockIdx.x * 128;

  f32x4 acc[4][4] = {};
  const __bf16* Ag = A  + (size_t)m0 * K;
  const __bf16* Bg = Bt + (size_t)n0 * K;

  for (int k0 = 0; k0 < K; k0 += 32) {
#pragma unroll
    for (int r = 0; r < 2; ++r) {
      const int c = r * 256 + tid;
      const int row = c >> 2, cc = (c & 3) * 8;
      load16_to_lds(Ag + (size_t)row * K + k0 + cc, &As[c * 8]);
      load16_to_lds(Bg + (size_t)row * K + k0 + cc, &Bs[c * 8]);
    }
    __syncthreads();
    bf16x8 af[4], bfr[4];
#pragma unroll
    for (int mt = 0; mt < 4; ++mt)
      af[mt] = *(const bf16x8*)&As[(wm * 64 + mt * 16 + l16) * 32 + quad * 8];
#pragma unroll
    for (int nt = 0; nt < 4; ++nt)
      bfr[nt] = *(const bf16x8*)&Bs[(wn * 64 + nt * 16 + l16) * 32 + quad * 8];
#pragma unroll
    for (int mt = 0; mt < 4; ++mt)
#pragma unroll
      for (int nt = 0; nt < 4; ++nt)
        acc[mt][nt] = __builtin_amdgcn_mfma_f32_16x16x32_bf16(af[mt], bfr[nt], acc[mt][nt], 0, 0, 0);
    __syncthreads();
  }

#pragma unroll
  for (int mt = 0; mt < 4; ++mt) {
#pragma unroll
    for (int nt = 0; nt < 4; ++nt) {
      const int col = n0 + wn * 64 + nt * 16 + l16;
#pragma unroll
      for (int i = 0; i < 4; ++i) {
        const int row = m0 + wm * 64 + mt * 16 + quad * 4 + i;
        float v = acc[mt][nt][i];
        const size_t idx = (size_t)row * N + col;
        if (EPI == EPI_BF16) {
          outb[idx] = (__bf16)v;
        } else if (EPI == EPI_RES_F32) {
          outf[idx] = v + res[idx];
        } else if (EPI == EPI_GELU_BF16) {
          v += bias[col];
          outb[idx] = (__bf16)(0.5f * v * (1.0f + erff(v * 0.70710678118f)));
        } else {
          v += bias[col];
          outf[idx] = v + res[idx];
        }
      }
    }
  }
}

// ---------------- RoPE for q,k: qkv(4096x3072) -> qr,kr [b][h][s][d] ----------------
__global__ __launch_bounds__(256) void rope_qk(
    const __bf16* __restrict__ qkv, __bf16* __restrict__ qr, __bf16* __restrict__ kr)
{
  const int idx = blockIdx.x * 256 + threadIdx.x; // (b,s,h,d2)
  const int d2 = idx & 31;
  const int h  = (idx >> 5) & 15;
  const int bs = idx >> 9;       // b*2048+s
  const int s  = bs & 2047;
  const int b  = bs >> 11;
  const float inv_freq = exp2f(-((float)d2 * (1.0f / 32.0f)) * 13.2877123795f); // log2(1e4)
  const float ang = (float)s * inv_freq;
  const float c = cosf(ang), sn = sinf(ang);
  const __bf16* qp = qkv + (size_t)bs * 3072 + h * 64 + 2 * d2;
  const __bf16* kp = qp + 1024;
  const float q0 = (float)qp[0], q1 = (float)qp[1];
  const float k0 = (float)kp[0], k1 = (float)kp[1];
  const size_t o = ((size_t)(b * 16 + h) * 2048 + s) * 64 + 2 * d2;
  qr[o]     = (__bf16)(q0 * c - q1 * sn);
  qr[o + 1] = (__bf16)(q1 * c + q0 * sn);
  kr[o]     = (__bf16)(k0 * c - k1 * sn);
  kr[o + 1] = (__bf16)(k1 * c + k0 * sn);
}

// ---------------- V transpose: qkv v-cols -> vt [b][h][d][s] ----------------
__global__ __launch_bounds__(256) void v_transpose(
    const __bf16* __restrict__ qkv, __bf16* __restrict__ vt)
{
  __shared__ __bf16 t[64][72];
  const int st = blockIdx.x, h = blockIdx.y, b = blockIdx.z;
  const int tx = threadIdx.x & 63, ty = threadIdx.x >> 6; // 64x4
  const int s0 = st * 64;
  const __bf16* src = qkv + ((size_t)(b * 2048 + s0)) * 3072 + 2048 + h * 64;
#pragma unroll
  for (int i = 0; i < 64; i += 4)
    t[ty + i][tx] = src[(size_t)(ty + i) * 3072 + tx];
  __syncthreads();
  __bf16* dst = vt + ((size_t)(b * 16 + h) * 64) * 2048 + s0;
#pragma unroll
  for (int i = 0; i < 64; i += 4)
    dst[(size_t)(ty + i) * 2048 + tx] = t[tx][ty + i];
}

// ---------------- flash attention: BQ=128, BK=64, online softmax ----------------
__global__ __launch_bounds__(256, 2) void attn_kernel(
    const __bf16* __restrict__ qr, const __bf16* __restrict__ kr,
    const __bf16* __restrict__ vt, __bf16* __restrict__ attn_o)
{
  constexpr int S = 2048, DH = 64, NH = 16, BQ = 128, BKK = 64;
  __shared__ __align__(16) char smem[69632];
  float*  Sc   = (float*)smem;                 // [128][65] (aliases Qs)
  __bf16* Qs   = (__bf16*)smem;                // [128][64]
  __bf16* Ks   = (__bf16*)(smem + 33280);      // [64][64]
  __bf16* Vts  = (__bf16*)(smem + 41472);      // [64][64]
  __bf16* Pb   = (__bf16*)(smem + 49664);      // [128][72]
  float*  mrow = (float*)(smem + 68096);
  float*  lrow = mrow + 128;
  float*  arow = lrow + 128;

  const int tid = threadIdx.x;
  const int lane = tid & 63, w = tid >> 6;
  const int quad = lane >> 4, l16 = lane & 15;
  const int qt = blockIdx.x, h = blockIdx.y, b = blockIdx.z;
  const int bh = b * NH + h;
  const __bf16* Q  = qr + ((size_t)bh * S + qt * BQ) * DH;
  const __bf16* Kp = kr + (size_t)bh * S * DH;
  const __bf16* Vp = vt + (size_t)bh * DH * S;

#pragma unroll
  for (int r = 0; r < 4; ++r) {
    const int c = r * 256 + tid;
    load16_to_lds(Q + c * 8, &Qs[c * 8]);
  }
  if (tid < 128) { mrow[tid] = -3.0e38f; lrow[tid] = 0.0f; }
  __syncthreads();

  bf16x8 qf[2][2];
#pragma unroll
  for (int mt = 0; mt < 2; ++mt)
#pragma unroll
    for (int ks = 0; ks < 2; ++ks)
      qf[mt][ks] = *(const bf16x8*)&Qs[(w * 32 + mt * 16 + l16) * 64 + ks * 32 + quad * 8];

  f32x4 oacc[2][4] = {};

  for (int kt = 0; kt < S / BKK; ++kt) {
    const int kk0 = kt * BKK;
    __syncthreads(); // prior-iter Pb/Vts/Ks reads done (iter0: after Qs frag reads)
#pragma unroll
    for (int r = 0; r < 2; ++r) {
      const int c = r * 256 + tid;
      load16_to_lds(Kp + (size_t)kk0 * DH + c * 8, &Ks[c * 8]);
      load16_to_lds(Vp + (size_t)(c >> 3) * S + kk0 + (c & 7) * 8, &Vts[c * 8]);
    }
    __syncthreads();

    // S = Q K^T * 1/8 -> Sc
#pragma unroll
    for (int mt = 0; mt < 2; ++mt) {
#pragma unroll
      for (int nt = 0; nt < 4; ++nt) {
        f32x4 sa = {};
#pragma unroll
        for (int ks = 0; ks < 2; ++ks) {
          const bf16x8 kf = *(const bf16x8*)&Ks[(nt * 16 + l16) * 64 + ks * 32 + quad * 8];
          sa = __builtin_amdgcn_mfma_f32_16x16x32_bf16(qf[mt][ks], kf, sa, 0, 0, 0);
        }
        const int colb = nt * 16 + l16;
        const int rowb = w * 32 + mt * 16 + quad * 4;
#pragma unroll
        for (int i = 0; i < 4; ++i)
          Sc[(rowb + i) * 65 + colb] = sa[i] * 0.125f;
      }
    }
    __syncthreads();

    // online softmax, 2 threads per row
    {
      const int row = tid >> 1, half = tid & 1;
      const float* sr = &Sc[row * 65 + half * 32];
      float mx = -3.0e38f;
#pragma unroll
      for (int c2 = 0; c2 < 32; ++c2) mx = fmaxf(mx, sr[c2]);
      mx = fmaxf(mx, __shfl_xor(mx, 1));
      const float mold = mrow[row];
      const float mnew = fmaxf(mold, mx);
      float sum = 0.0f;
      __bf16* pr = &Pb[row * 72 + half * 32];
#pragma unroll
      for (int c2 = 0; c2 < 32; ++c2) {
        const float p = __expf(sr[c2] - mnew);
        pr[c2] = (__bf16)p;
        sum += p;
      }
      sum += __shfl_xor(sum, 1);
      if (half == 0) {
        arow[row] = __expf(mold - mnew);
        mrow[row] = mnew;
        lrow[row] = lrow[row] * arow[row] + sum;
      }
    }
    __syncthreads();

    // rescale O, then O += P V
#pragma unroll
    for (int mt = 0; mt < 2; ++mt) {
      const int rowb = w * 32 + mt * 16 + quad * 4;
#pragma unroll
      for (int i = 0; i < 4; ++i) {
        const float a = arow[rowb + i];
#pragma unroll
        for (int nt = 0; nt < 4; ++nt) oacc[mt][nt][i] *= a;
      }
    }
#pragma unroll
    for (int mt = 0; mt < 2; ++mt) {
#pragma unroll
      for (int ks = 0; ks < 2; ++ks) {
        const bf16x8 pf = *(const bf16x8*)&Pb[(w * 32 + mt * 16 + l16) * 72 + ks * 32 + quad * 8];
#pragma unroll
        for (int nt = 0; nt < 4; ++nt) {
          const bf16x8 vf = *(const bf16x8*)&Vts[(nt * 16 + l16) * 64 + ks * 32 + quad * 8];
          oacc[mt][nt] = __builtin_amdgcn_mfma_f32_16x16x32_bf16(pf, vf, oacc[mt][nt], 0, 0, 0);
        }
      }
    }
  }

  // epilogue: /l, store to (b*S+s, h*64+d)
#pragma unroll
  for (int mt = 0; mt < 2; ++mt) {
    const int rowb = w * 32 + mt * 16 + quad * 4;
#pragma unroll
    for (int i = 0; i < 4; ++i) {
      const float linv = 1.0f / lrow[rowb + i];
      const int srow = qt * BQ + rowb + i;
      const size_t orow = ((size_t)b * S + srow) * 1024 + h * 64;
#pragma unroll
      for (int nt = 0; nt < 4; ++nt)
        attn_o[orow + nt * 16 + l16] = (__bf16)(oacc[mt][nt][i] * linv);
    }
  }
}

// ---------------- launch ----------------
extern "C" void kernel_launch(void* const* d_in, const int* in_sizes, int n_in,
                              void* d_out, int out_size, void* d_ws, size_t ws_size,
                              hipStream_t stream) {
  const float* inputs = (const float*)d_in[0];
  const float* ln1_g  = (const float*)d_in[1];
  const float* ln1_b  = (const float*)d_in[2];
  const float* Wq     = (const float*)d_in[3];
  const float* Wk     = (const float*)d_in[4];
  const float* Wv     = (const float*)d_in[5];
  const float* Wo     = (const float*)d_in[6];
  const float* ln2_g  = (const float*)d_in[7];
  const float* ln2_b  = (const float*)d_in[8];
  const float* Wfc2   = (const float*)d_in[9];
  const float* bfc2   = (const float*)d_in[10];
  const float* Wfc3   = (const float*)d_in[11];
  const float* bfc3   = (const float*)d_in[12];
  float* out = (float*)d_out;
  char* ws = (char*)d_ws;
  const size_t MB = 1024 * 1024;

  __bf16* Wqkv_t = (__bf16*)(ws);            // 6 MB: [3072][1024]
  __bf16* Wo_t   = (__bf16*)(ws + 6 * MB);   // 2 MB
  __bf16* Wfc2_t = (__bf16*)(ws + 8 * MB);   // 8 MB: [4096][1024]
  __bf16* Wfc3_t = (__bf16*)(ws + 16 * MB);  // 8 MB: [1024][4096]
  __bf16* xb     = (__bf16*)(ws + 24 * MB);  // 8 MB; reused as attn_o
  __bf16* attn_o = xb;
  __bf16* qkv    = (__bf16*)(ws + 32 * MB);  // 24 MB; reused:
  float*  mlp_in = (float*)(ws + 32 * MB);   //   16 MB
  __bf16* h2     = (__bf16*)(ws + 48 * MB);  //   8 MB
  __bf16* qrb    = (__bf16*)(ws + 56 * MB);  // 8 MB; qr/kr/vt reused as hbuf
  __bf16* krb    = (__bf16*)(ws + 64 * MB);
  __bf16* vtb    = (__bf16*)(ws + 72 * MB);
  __bf16* hbuf   = (__bf16*)(ws + 56 * MB);  // 32 MB (after attention)

  const dim3 tb(32, 8);
  transpose_cast<<<dim3(32, 32),  tb, 0, stream>>>(Wq,   Wqkv_t,                1024, 1024);
  transpose_cast<<<dim3(32, 32),  tb, 0, stream>>>(Wk,   Wqkv_t + 1024 * 1024,  1024, 1024);
  transpose_cast<<<dim3(32, 32),  tb, 0, stream>>>(Wv,   Wqkv_t + 2048 * 1024,  1024, 1024);
  transpose_cast<<<dim3(32, 32),  tb, 0, stream>>>(Wo,   Wo_t,                  1024, 1024);
  transpose_cast<<<dim3(128, 32), tb, 0, stream>>>(Wfc2, Wfc2_t,                1024, 4096);
  transpose_cast<<<dim3(32, 128), tb, 0, stream>>>(Wfc3, Wfc3_t,                4096, 1024);

  ln_kernel<<<4096, 256, 0, stream>>>(inputs, ln1_g, ln1_b, xb);

  gemm_bf16<EPI_BF16><<<dim3(24, 32), 256, 0, stream>>>(
      xb, Wqkv_t, qkv, nullptr, nullptr, nullptr, 4096, 3072, 1024);

  rope_qk<<<8192, 256, 0, stream>>>(qkv, qrb, krb);
  v_transpose<<<dim3(32, 16, 2), 256, 0, stream>>>(qkv, vtb);

  attn_kernel<<<dim3(16, 16, 2), 256, 0, stream>>>(qrb, krb, vtb, attn_o);

  gemm_bf16<EPI_RES_F32><<<dim3(8, 32), 256, 0, stream>>>(
      attn_o, Wo_t, nullptr, mlp_in, nullptr, inputs, 4096, 1024, 1024);

  ln_kernel<<<4096, 256, 0, stream>>>(mlp_in, ln2_g, ln2_b, h2);

  gemm_bf16<EPI_GELU_BF16><<<dim3(32, 32), 256, 0, stream>>>(
      h2, Wfc2_t, hbuf, nullptr, bfc2, nullptr, 4096, 4096, 1024);

  gemm_bf16<EPI_BIAS_RES_F32><<<dim3(8, 32), 256, 0, stream>>>(
      hbuf, Wfc3_t, nullptr, out, bfc3, mlp_in, 4096, 1024, 4096);
}